// Round 1
// 74.892 us; speedup vs baseline: 1.1074x; 1.1074x over previous
//
#include <hip/hip_runtime.h>

// Chamfer loss between subsampled point clouds (exact-form distances).
// srcA: (64000,2) fp32 -> A = 8000 pts  (fp32 linspace trunc, matches jnp)
// srcB: (80000,2) fp32 -> B = 10000 pts
// out  = 0.5 * ( mean_i min_j |A_i - B_j| + mean_j min_i |A_i - B_j| )
//
// Two dispatches:
//  1) chamfer_partial: flat grid covering BOTH directions. Each block owns
//     (row-group of 512, column-chunk of 256). Columns staged in LDS
//     (broadcast reads -> conflict-free). 2 rows/thread.
//     Hot path: cn==CHUNK specialization -> compile-time 256-trip loop with
//     explicit float4 LDS reads (ds_read_b128) + unroll so the compiler can
//     batch/hoist LDS reads ahead of the 20-VALU blocks (no exposed lgkm
//     latency). Grid = 1280 blocks = exactly 5 blocks/CU (5 waves/SIMD):
//     balanced, no 2-vs-3 block tail.
//     Partial min of SQUARED distance direct-stored per (row, chunk) -> no
//     atomics, no init needed. Block 0 zeroes d_out for the reduce.
//  2) reduce_out: min over chunks per row, sqrt, scaled sum, per-block
//     atomicAdd into d_out (sqrt is monotone so applied after the min).

#define SRC_A 64000
#define SRC_B 80000
#define NA 8000
#define NB 10000

#define BLOCK 256
#define CHUNK 256          // columns staged in LDS per block
#define RPT 2              // rows per thread
#define RPB (BLOCK * RPT)  // 512 rows per block

#define NB1X 16   // ceil(8000/512)    row-groups, pass 1
#define NB1Y 40   // ceil(10000/256)   col-chunks, pass 1
#define NB2X 20   // ceil(10000/512)   row-groups, pass 2
#define NB2Y 32   // ceil(8000/256)    col-chunks, pass 2
#define NBLK1 (NB1X * NB1Y)           // 640
#define NBLK2 (NB2X * NB2Y)           // 640

#define P1_STRIDE (NB1X * RPB)        // 8192 (padded row count, pass 1)
#define P2_STRIDE (NB2X * RPB)        // 10240
// ws layout: P1 float[NB1Y * P1_STRIDE] @ 0 (1310720 B);
//            P2 float[NB2Y * P2_STRIDE] @ 1310720 (1310720 B)
#define P2_OFF 1310720

__global__ __launch_bounds__(BLOCK) void chamfer_partial(
        const float2* __restrict__ srcA, const float2* __restrict__ srcB,
        float* __restrict__ ws, float* __restrict__ out) {
    if (blockIdx.x == 0 && threadIdx.x == 0) *out = 0.0f;  // init for reduce's atomicAdd

    const bool pass1 = (int)blockIdx.x < NBLK1;
    const float2* srcRows; const float2* srcCols;
    float rowDelta, colDelta;
    int rowSrcMax, colSrcMax, nrows, ncols, bx, by, pstride;
    float* P;
    if (pass1) {
        int f = (int)blockIdx.x;
        bx = f % NB1X; by = f / NB1X;
        srcRows = srcA; rowDelta = (float)(SRC_A - 1) / (float)(NA - 1);
        rowSrcMax = SRC_A - 1; nrows = NA;
        srcCols = srcB; colDelta = (float)(SRC_B - 1) / (float)(NB - 1);
        colSrcMax = SRC_B - 1; ncols = NB;
        P = ws; pstride = P1_STRIDE;
    } else {
        int f = (int)blockIdx.x - NBLK1;
        bx = f % NB2X; by = f / NB2X;
        srcRows = srcB; rowDelta = (float)(SRC_B - 1) / (float)(NB - 1);
        rowSrcMax = SRC_B - 1; nrows = NB;
        srcCols = srcA; colDelta = (float)(SRC_A - 1) / (float)(NA - 1);
        colSrcMax = SRC_A - 1; ncols = NA;
        P = ws + (P2_OFF / 4); pstride = P2_STRIDE;
    }

    __shared__ __align__(16) float2 sc[CHUNK];
    int c0 = by * CHUNK;
    int cn = ncols - c0; if (cn > CHUNK) cn = CHUNK;
    int j = (int)threadIdx.x;
    if (j < cn) {
        int cidx = (int)((float)(c0 + j) * colDelta);
        if (cidx > colSrcMax) cidx = colSrcMax;
        sc[j] = srcCols[cidx];
    }
    __syncthreads();

    // 2 rows per thread: r_i = bx*512 + i*256 + tid  (coalesced stores)
    float2 p[RPT];
    float  m[RPT];
    int r0 = bx * RPB + (int)threadIdx.x;
#pragma unroll
    for (int i = 0; i < RPT; ++i) {
        int r = r0 + i * BLOCK;
        int l = r < nrows ? r : nrows - 1;               // clamp for load; guard store
        int ridx = (int)((float)l * rowDelta);
        if (ridx > rowSrcMax) ridx = rowSrcMax;
        p[i] = srcRows[ridx];
        m[i] = __builtin_inff();
    }

    if (cn == CHUNK) {
        // hot path (70 of 72 chunks): compile-time trip count, b128 LDS reads
        const float4* sc4 = reinterpret_cast<const float4*>(sc);
#pragma unroll 4
        for (int kk = 0; kk < CHUNK / 2; ++kk) {
            float4 q = sc4[kk];  // two columns: (q.x,q.y) and (q.z,q.w)
#pragma unroll
            for (int i = 0; i < RPT; ++i) {
                float dx0 = p[i].x - q.x, dy0 = p[i].y - q.y;
                m[i] = fminf(m[i], fmaf(dx0, dx0, dy0 * dy0));
                float dx1 = p[i].x - q.z, dy1 = p[i].y - q.w;
                m[i] = fminf(m[i], fmaf(dx1, dx1, dy1 * dy1));
            }
        }
    } else {
        for (int k = 0; k < cn; ++k) {
            float2 q = sc[k];
#pragma unroll
            for (int i = 0; i < RPT; ++i) {
                float dx = p[i].x - q.x, dy = p[i].y - q.y;
                m[i] = fminf(m[i], fmaf(dx, dx, dy * dy));
            }
        }
    }

#pragma unroll
    for (int i = 0; i < RPT; ++i) {
        int r = r0 + i * BLOCK;
        if (r < nrows) P[by * pstride + r] = m[i];
    }
}

__global__ __launch_bounds__(BLOCK) void reduce_out(const float* __restrict__ ws,
                                                    float* __restrict__ out) {
    const float* P1 = ws;
    const float* P2 = ws + (P2_OFF / 4);
    float s = 0.0f;
    for (int t = (int)(blockIdx.x * BLOCK + threadIdx.x); t < NA + NB;
         t += (int)(gridDim.x * BLOCK)) {
        float mn = __builtin_inff();
        if (t < NA) {
#pragma unroll
            for (int c = 0; c < NB1Y; ++c) mn = fminf(mn, P1[c * P1_STRIDE + t]);
            s += sqrtf(mn) * (0.5f / (float)NA);
        } else {
            int r = t - NA;
#pragma unroll
            for (int c = 0; c < NB2Y; ++c) mn = fminf(mn, P2[c * P2_STRIDE + r]);
            s += sqrtf(mn) * (0.5f / (float)NB);
        }
    }
    // wave shuffle reduce, then LDS across the 4 waves, then one atomicAdd
    for (int off = 32; off > 0; off >>= 1) s += __shfl_down(s, off, 64);
    __shared__ float red[4];
    int wave = (int)threadIdx.x >> 6;
    if ((threadIdx.x & 63) == 0) red[wave] = s;
    __syncthreads();
    if (threadIdx.x == 0) {
        float t = red[0] + red[1] + red[2] + red[3];
        atomicAdd(out, t);
    }
}

extern "C" void kernel_launch(void* const* d_in, const int* in_sizes, int n_in,
                              void* d_out, int out_size, void* d_ws, size_t ws_size,
                              hipStream_t stream) {
    (void)in_sizes; (void)n_in; (void)out_size; (void)ws_size;
    const float2* srcA = (const float2*)d_in[0];  // img_render_points (1000*64*2)
    const float2* srcB = (const float2*)d_in[1];  // ref point cloud (80000*2)
    float* ws = (float*)d_ws;
    float* out = (float*)d_out;

    chamfer_partial<<<NBLK1 + NBLK2, BLOCK, 0, stream>>>(srcA, srcB, ws, out);
    reduce_out<<<64, BLOCK, 0, stream>>>(ws, out);
}